// Round 10
// baseline (313.683 us; speedup 1.0000x reference)
//
#include <hip/hip_runtime.h>
#include <hip/hip_cooperative_groups.h>
#include <hip/hip_fp16.h>
#include <math.h>

namespace cg = cooperative_groups;
typedef unsigned long long ull;

#define DIM  64
#define SPAN 256            // nodes per bucket (dst>>8)
#define SPAN_SHIFT 8
#define KMAX 512            // max buckets
#define CAP  6144           // LDS staging capacity per bucket
#define TPB  1024
#define GRID 256            // coop grid: 1 block/CU guaranteed resident

// LDS arena layout (bytes):
//   [0,49152)        srec  (CAP ull)          P4
//   [49152,61440)    sidx  (CAP u16)          P4
//   [61440,62464)    hcnt  (SPAN int)         P4
//   [62464,64512)    hoff  (2*SPAN int)       P4
//   [64512,65536)    lcur  (SPAN int)         P4
//   [65536,66560)    nstart(SPAN int)         P4
//   P0/P1 overlay: lh[K<=512]  P2 overlay: buf[2*1024]  P3 overlay: lcur[K]
#define SMEM_BYTES 66560

__global__ __launch_bounds__(TPB) void fused_kernel(
        const float* __restrict__ x,
        const float* __restrict__ w_src,
        const float* __restrict__ w_dst,
        const float* __restrict__ ew,
        const int* __restrict__ src_idx,
        const int* __restrict__ dst_idx,
        float* __restrict__ a_src,
        float* __restrict__ a_dst,
        __half* __restrict__ xh,
        int* __restrict__ moffs,          // K*GRID ints
        int* __restrict__ bsum,           // NBs ints
        ull* __restrict__ pay,            // E
        float* __restrict__ h,
        int N, int E, int K, int NBs) {
    cg::grid_group grid = cg::this_grid();
    const int G   = gridDim.x;            // == GRID
    const int b   = blockIdx.x;
    const int tid = threadIdx.x;
    __shared__ __align__(16) char smem[SMEM_BYTES];

    // ---------------- P0: score (+xh emit)  |  P1: private histogram -------
    {
        int* lh = (int*)smem;
        for (int j = tid; j < K; j += TPB) lh[j] = 0;
        __syncthreads();
        int lane = tid & 63;
        for (int node = b * 16 + (tid >> 6); node < N; node += G * 16) {
            float xv = x[(size_t)node * DIM + lane];
            xh[(size_t)node * DIM + lane] = __float2half_rn(xv);
            float s1 = xv * w_src[lane];
            float s2 = xv * w_dst[lane];
            #pragma unroll
            for (int off = 32; off > 0; off >>= 1) {
                s1 += __shfl_down(s1, off, 64);
                s2 += __shfl_down(s2, off, 64);
            }
            if (lane == 0) { a_src[node] = s1; a_dst[node] = s2; }
        }
        for (int e = b * TPB + tid; e < E; e += G * TPB) {
            unsigned t = (unsigned)dst_idx[e];
            if (t >= (unsigned)N) t = 0;              // guard
            atomicAdd(&lh[t >> SPAN_SHIFT], 1);
        }
        __syncthreads();
        for (int j = tid; j < K; j += TPB) moffs[j * G + b] = lh[j];
    }
    grid.sync();

    // ---------------- P2: per-chunk exclusive scan (chunk = 1024) ----------
    int Ntot = K * G;
    if (b < NBs) {
        int* buf = (int*)smem;                        // 2*1024 ints
        int i = b * TPB + tid;
        int v = (i < Ntot) ? moffs[i] : 0;
        int sel = 0;
        buf[tid] = v;
        __syncthreads();
        for (int off = 1; off < TPB; off <<= 1) {
            int nsel = sel ^ 1;
            int add = (tid >= off) ? buf[sel * TPB + tid - off] : 0;
            buf[nsel * TPB + tid] = buf[sel * TPB + tid] + add;
            __syncthreads();
            sel = nsel;
        }
        if (i < Ntot) moffs[i] = buf[sel * TPB + tid] - v;   // exclusive
        if (tid == TPB - 1) bsum[b] = buf[sel * TPB + tid];  // chunk total
    }
    grid.sync();

    // ---------------- P2b: top-level exclusive scan of chunk sums ---------
    if (b == 0) {
        int* buf = (int*)smem;
        int v = (tid < NBs) ? bsum[tid] : 0;
        int sel = 0;
        buf[tid] = v;
        __syncthreads();
        for (int off = 1; off < TPB; off <<= 1) {
            int nsel = sel ^ 1;
            int add = (tid >= off) ? buf[sel * TPB + tid - off] : 0;
            buf[nsel * TPB + tid] = buf[sel * TPB + tid] + add;
            __syncthreads();
            sel = nsel;
        }
        if (tid < NBs) bsum[tid] = buf[sel * TPB + tid] - v;
    }
    grid.sync();

    // ---------------- P3: binpass — bucket-grouped payload -----------------
    {
        int* lcur = (int*)smem;                       // K ints
        for (int j = tid; j < K; j += TPB) {
            int i = j * G + b;
            lcur[j] = moffs[i] + bsum[i >> 10];
        }
        __syncthreads();
        for (int e = b * TPB + tid; e < E; e += G * TPB) {
            unsigned s = (unsigned)src_idx[e];
            unsigned t = (unsigned)dst_idx[e];
            if (s >= (unsigned)N) s = 0;              // guard
            if (t >= (unsigned)N) t = 0;              // guard
            float a = tanhf(a_src[s] + a_dst[t]) * ew[e];
            int bk = (int)(t >> SPAN_SHIFT);
            int pos = atomicAdd(&lcur[bk], 1);        // LDS cursor, block-local
            unsigned rec = (s << 8) | (t & (SPAN - 1u));
            pay[pos] = ((ull)rec << 32) | (ull)__float_as_uint(a);
        }
    }
    grid.sync();

    // ---------------- P4: per-bucket sort + gather (bucket-stride loop) ----
    ull* srec            = (ull*)smem;
    unsigned short* sidx = (unsigned short*)(smem + CAP * 8);
    int* hcnt            = (int*)(smem + CAP * 8 + CAP * 2);
    int* hoff            = (int*)(smem + CAP * 8 + CAP * 2 + SPAN * 4);
    int* lcur4           = (int*)(smem + CAP * 8 + CAP * 2 + SPAN * 4 * 3);
    int* nstart          = (int*)(smem + CAP * 8 + CAP * 2 + SPAN * 4 * 4);

    for (int bkt = b; bkt < K; bkt += G) {
        __syncthreads();                              // LDS reuse across iters
        int i0 = bkt * G;
        int bstart = moffs[i0] + bsum[i0 >> 10];
        int bend;
        if (bkt == K - 1) bend = E;
        else { int i1 = (bkt + 1) * G; bend = moffs[i1] + bsum[i1 >> 10]; }
        int cnt = bend - bstart;

        if (cnt <= CAP) {
            // ---- stage + histogram ----
            if (tid < SPAN) hcnt[tid] = 0;
            __syncthreads();
            for (int i = tid; i < cnt; i += TPB) {
                ull r = pay[bstart + i];
                srec[i] = r;
                atomicAdd(&hcnt[(int)((r >> 32) & (SPAN - 1u))], 1);
            }
            __syncthreads();
            // ---- inclusive scan of hcnt[SPAN] ----
            int sel = 0;
            if (tid < SPAN) hoff[tid] = hcnt[tid];
            __syncthreads();
            for (int off = 1; off < SPAN; off <<= 1) {
                int nsel = sel ^ 1;
                if (tid < SPAN)
                    hoff[nsel * SPAN + tid] = hoff[sel * SPAN + tid] +
                        ((tid >= off) ? hoff[sel * SPAN + tid - off] : 0);
                __syncthreads();
                sel = nsel;
            }
            if (tid < SPAN) {
                int excl = hoff[sel * SPAN + tid] - hcnt[tid];
                nstart[tid] = excl;
                lcur4[tid]  = excl;
            }
            __syncthreads();
            // ---- permute indices only (sidx), srec stays put ----
            for (int i = tid; i < cnt; i += TPB) {
                ull r = srec[i];
                int d = (int)((r >> 32) & (SPAN - 1u));
                int pos = atomicAdd(&lcur4[d], 1);
                sidx[pos] = (unsigned short)i;
            }
            __syncthreads();
            // ---- gather: 4 nodes/wave, 4 edges/iter ----
            int lane = tid & 63;
            int wave = tid >> 6;                      // 16 waves
            int grp  = lane >> 4;                     // node slot 0..3
            int sub  = lane & 15;                     // dim quad
            for (int d0 = (wave << 2); d0 < SPAN; d0 += 64) {
                int d = d0 + grp;
                int node = bkt * SPAN + d;
                int p  = nstart[d];
                int pe = p + hcnt[d];
                if (node >= N) pe = p;                // dead node: no work
                float ax = 0.f, ay = 0.f, az = 0.f, aw = 0.f;
                while (p + 4 <= pe) {
                    ull r0 = srec[sidx[p]];
                    ull r1 = srec[sidx[p + 1]];
                    ull r2 = srec[sidx[p + 2]];
                    ull r3 = srec[sidx[p + 3]];
                    p += 4;
                    unsigned s0 = (unsigned)(r0 >> 40); if (s0 >= (unsigned)N) s0 = 0;
                    unsigned s1 = (unsigned)(r1 >> 40); if (s1 >= (unsigned)N) s1 = 0;
                    unsigned s2 = (unsigned)(r2 >> 40); if (s2 >= (unsigned)N) s2 = 0;
                    unsigned s3 = (unsigned)(r3 >> 40); if (s3 >= (unsigned)N) s3 = 0;
                    uint2 v0 = *(const uint2*)(xh + (size_t)s0 * DIM + (sub << 2));
                    uint2 v1 = *(const uint2*)(xh + (size_t)s1 * DIM + (sub << 2));
                    uint2 v2 = *(const uint2*)(xh + (size_t)s2 * DIM + (sub << 2));
                    uint2 v3 = *(const uint2*)(xh + (size_t)s3 * DIM + (sub << 2));
                    float a0 = __uint_as_float((unsigned)r0);
                    float a1 = __uint_as_float((unsigned)r1);
                    float a2 = __uint_as_float((unsigned)r2);
                    float a3 = __uint_as_float((unsigned)r3);
                    float2 lo0 = __half22float2(*(const __half2*)&v0.x);
                    float2 hi0 = __half22float2(*(const __half2*)&v0.y);
                    float2 lo1 = __half22float2(*(const __half2*)&v1.x);
                    float2 hi1 = __half22float2(*(const __half2*)&v1.y);
                    float2 lo2 = __half22float2(*(const __half2*)&v2.x);
                    float2 hi2 = __half22float2(*(const __half2*)&v2.y);
                    float2 lo3 = __half22float2(*(const __half2*)&v3.x);
                    float2 hi3 = __half22float2(*(const __half2*)&v3.y);
                    ax = fmaf(a0, lo0.x, ax); ay = fmaf(a0, lo0.y, ay);
                    az = fmaf(a0, hi0.x, az); aw = fmaf(a0, hi0.y, aw);
                    ax = fmaf(a1, lo1.x, ax); ay = fmaf(a1, lo1.y, ay);
                    az = fmaf(a1, hi1.x, az); aw = fmaf(a1, hi1.y, aw);
                    ax = fmaf(a2, lo2.x, ax); ay = fmaf(a2, lo2.y, ay);
                    az = fmaf(a2, hi2.x, az); aw = fmaf(a2, hi2.y, aw);
                    ax = fmaf(a3, lo3.x, ax); ay = fmaf(a3, lo3.y, ay);
                    az = fmaf(a3, hi3.x, az); aw = fmaf(a3, hi3.y, aw);
                }
                if (p < pe) {                         // masked tail quad
                    int q1 = p + 1, q2 = p + 2, q3 = p + 3;
                    ull r0 = srec[sidx[p]];
                    ull r1 = (q1 < pe) ? srec[sidx[q1]] : 0ULL;
                    ull r2 = (q2 < pe) ? srec[sidx[q2]] : 0ULL;
                    ull r3 = (q3 < pe) ? srec[sidx[q3]] : 0ULL;
                    unsigned s0 = (unsigned)(r0 >> 40); if (s0 >= (unsigned)N) s0 = 0;
                    unsigned s1 = (unsigned)(r1 >> 40); if (s1 >= (unsigned)N) s1 = 0;
                    unsigned s2 = (unsigned)(r2 >> 40); if (s2 >= (unsigned)N) s2 = 0;
                    unsigned s3 = (unsigned)(r3 >> 40); if (s3 >= (unsigned)N) s3 = 0;
                    uint2 v0 = *(const uint2*)(xh + (size_t)s0 * DIM + (sub << 2));
                    uint2 v1 = *(const uint2*)(xh + (size_t)s1 * DIM + (sub << 2));
                    uint2 v2 = *(const uint2*)(xh + (size_t)s2 * DIM + (sub << 2));
                    uint2 v3 = *(const uint2*)(xh + (size_t)s3 * DIM + (sub << 2));
                    float a0 = __uint_as_float((unsigned)r0);
                    float a1 = __uint_as_float((unsigned)r1);
                    float a2 = __uint_as_float((unsigned)r2);
                    float a3 = __uint_as_float((unsigned)r3);
                    float2 lo0 = __half22float2(*(const __half2*)&v0.x);
                    float2 hi0 = __half22float2(*(const __half2*)&v0.y);
                    float2 lo1 = __half22float2(*(const __half2*)&v1.x);
                    float2 hi1 = __half22float2(*(const __half2*)&v1.y);
                    float2 lo2 = __half22float2(*(const __half2*)&v2.x);
                    float2 hi2 = __half22float2(*(const __half2*)&v2.y);
                    float2 lo3 = __half22float2(*(const __half2*)&v3.x);
                    float2 hi3 = __half22float2(*(const __half2*)&v3.y);
                    ax = fmaf(a0, lo0.x, ax); ay = fmaf(a0, lo0.y, ay);
                    az = fmaf(a0, hi0.x, az); aw = fmaf(a0, hi0.y, aw);
                    ax = fmaf(a1, lo1.x, ax); ay = fmaf(a1, lo1.y, ay);
                    az = fmaf(a1, hi1.x, az); aw = fmaf(a1, hi1.y, aw);
                    ax = fmaf(a2, lo2.x, ax); ay = fmaf(a2, lo2.y, ay);
                    az = fmaf(a2, hi2.x, az); aw = fmaf(a2, hi2.y, aw);
                    ax = fmaf(a3, lo3.x, ax); ay = fmaf(a3, lo3.y, ay);
                    az = fmaf(a3, hi3.x, az); aw = fmaf(a3, hi3.y, aw);
                }
                if (node < N) {
                    *(float4*)(h + (size_t)node * DIM + (sub << 2)) =
                        make_float4(ax, ay, az, aw);
                }
            }
        } else {
            // ---- slow path (cnt > CAP): atomic accumulate (fp32 x) ----
            for (int j = tid; j < SPAN * DIM; j += TPB) {
                int node = bkt * SPAN + (j >> 6);
                if (node < N) h[(size_t)node * DIM + (j & 63)] = 0.f;
            }
            __syncthreads();
            for (int i = tid; i < cnt; i += TPB) {
                ull r = pay[bstart + i];
                unsigned s = (unsigned)(r >> 40);
                if (s >= (unsigned)N) s = 0;
                int node = bkt * SPAN + (int)((r >> 32) & (SPAN - 1u));
                float a = __uint_as_float((unsigned)r);
                if (node < N)
                    for (int k = 0; k < DIM; ++k)
                        atomicAdd(&h[(size_t)node * DIM + k],
                                  a * x[(size_t)s * DIM + k]);
            }
        }
    }
}

// ---------------- Fallback (atomic path, known-good) -----------------------
__global__ void zero_h_kernel(float* __restrict__ p, int n) {
    int i = blockIdx.x * blockDim.x + threadIdx.x;
    if (i < n) p[i] = 0.f;
}

__global__ void edge_kernel_atomic(const float* __restrict__ x,
                                   const float* __restrict__ ew,
                                   const int* __restrict__ src_idx,
                                   const int* __restrict__ dst_idx,
                                   const float* __restrict__ a_src,
                                   const float* __restrict__ a_dst,
                                   float* __restrict__ h,
                                   int E) {
    int gid  = blockIdx.x * blockDim.x + threadIdx.x;
    int e    = gid >> 6;
    int lane = threadIdx.x & 63;
    if (e >= E) return;
    int s = src_idx[e];
    int t = dst_idx[e];
    float a  = tanhf(a_src[s] + a_dst[t]) * ew[e];
    float xv = x[(size_t)s * DIM + lane];
    atomicAdd(&h[(size_t)t * DIM + lane], a * xv);
}

__global__ void score_only_kernel(const float* __restrict__ x,
                                  const float* __restrict__ w_src,
                                  const float* __restrict__ w_dst,
                                  float* __restrict__ a_src,
                                  float* __restrict__ a_dst,
                                  int N) {
    int gid  = blockIdx.x * blockDim.x + threadIdx.x;
    int node = gid >> 6;
    int lane = threadIdx.x & 63;
    if (node >= N) return;
    float xv = x[(size_t)node * DIM + lane];
    float s1 = xv * w_src[lane];
    float s2 = xv * w_dst[lane];
    #pragma unroll
    for (int off = 32; off > 0; off >>= 1) {
        s1 += __shfl_down(s1, off, 64);
        s2 += __shfl_down(s2, off, 64);
    }
    if (lane == 0) {
        a_src[node] = s1;
        a_dst[node] = s2;
    }
}

static void run_fallback(const float* x, const float* w_src,
                         const float* w_dst, const float* ew,
                         const int* src, const int* dst,
                         float* a_src, float* a_dst, float* h,
                         int N, int E, int out_size, hipStream_t stream) {
    int score_blocks = (N + 3) / 4;
    score_only_kernel<<<score_blocks, 256, 0, stream>>>(x, w_src, w_dst,
                                                        a_src, a_dst, N);
    int ob = (out_size + 255) / 256;
    zero_h_kernel<<<ob, 256, 0, stream>>>(h, out_size);
    int edge_blocks = (E + 3) / 4;
    edge_kernel_atomic<<<edge_blocks, 256, 0, stream>>>(x, ew, src, dst,
                                                        a_src, a_dst, h, E);
}

extern "C" void kernel_launch(void* const* d_in, const int* in_sizes, int n_in,
                              void* d_out, int out_size, void* d_ws, size_t ws_size,
                              hipStream_t stream) {
    const float* x     = (const float*)d_in[0];
    const float* w_src = (const float*)d_in[1];
    const float* w_dst = (const float*)d_in[2];
    const float* ew    = (const float*)d_in[3];
    const int*   src   = (const int*)d_in[4];
    const int*   dst   = (const int*)d_in[5];
    float* h = (float*)d_out;

    int N = in_sizes[0] / DIM;
    int E = in_sizes[3];

    int K    = (N + SPAN - 1) / SPAN;         // buckets
    int G    = GRID;                          // coop grid size (1 block/CU)
    int Ntot = K * G;                         // private-hist matrix entries
    int NBs  = (Ntot + TPB - 1) / TPB;        // scan chunks (chunk = 1024)

    // ws layout (4B units):
    // [a_src N][a_dst N][moffs Ntot][bsum NBs][pad][pay E*8B][xh N*DIM*2B]
    float* a_src  = (float*)d_ws;
    float* a_dst  = a_src + N;
    int*   moffs  = (int*)(a_dst + N);
    int*   bsum   = moffs + Ntot;
    size_t head_bytes = ((size_t)(2 * N) + (size_t)Ntot + (size_t)NBs) * 4;
    size_t pay_off = (head_bytes + 15) & ~(size_t)15;
    ull* pay = (ull*)((char*)d_ws + pay_off);
    size_t xh_off = pay_off + (size_t)E * 8;
    __half* xh = (__half*)((char*)d_ws + xh_off);
    size_t need = xh_off + (size_t)N * DIM * 2;

    if (ws_size < need || K > KMAX || K < 1 || NBs > G ||
        (N * DIM) % 2 != 0) {
        run_fallback(x, w_src, w_dst, ew, src, dst, a_src, a_dst, h,
                     N, E, out_size, stream);
        return;
    }

    void* args[] = {
        (void*)&x, (void*)&w_src, (void*)&w_dst, (void*)&ew,
        (void*)&src, (void*)&dst,
        (void*)&a_src, (void*)&a_dst, (void*)&xh,
        (void*)&moffs, (void*)&bsum, (void*)&pay, (void*)&h,
        (void*)&N, (void*)&E, (void*)&K, (void*)&NBs
    };
    hipError_t err = hipLaunchCooperativeKernel((const void*)fused_kernel,
                                                dim3(G), dim3(TPB), args, 0,
                                                stream);
    if (err != hipSuccess) {
        run_fallback(x, w_src, w_dst, ew, src, dst, a_src, a_dst, h,
                     N, E, out_size, stream);
    }
}